// Round 5
// baseline (218.411 us; speedup 1.0000x reference)
//
#include <hip/hip_runtime.h>
#include <hip/hip_bf16.h>

// ---------------------------------------------------------------------------
// InferCellV2 R5: bf16 MFMA implicit GEMM. A in LDS (XOR-swizzled, verified
// conflict-free), B fragments DIRECT FROM GLOBAL (L1-resident 8KB tap) with a
// 1-tap register double buffer => inner tap loop has NO barriers and half the
// LDS read traffic of R4 (64KB/tap/CU ~768cyc < MFMA 1241cyc). Barriers only
// at per-src A-tile swaps (2 per switch).
// Activations: zero-padded NHWC bf16 [B][34][34][64], 16B channel chunks
// permuted: chunk cb of pixel p at p*128+((cb^(p&7))*16). Weights PLAIN
// [l][tap][o][i] (swizzle unnecessary outside LDS).
// conv_stage: 256 thr / 4 waves / 8 output rows / grid 512 (2 blocks/CU).
// Wave tile 64px x 64oc = 4x4 MFMA 16x16x32, 64 acc VGPRs.
// ---------------------------------------------------------------------------

typedef __bf16 bf16x8 __attribute__((ext_vector_type(8)));
typedef float floatx4 __attribute__((ext_vector_type(4)));
typedef unsigned int uint32;

#define PADW 34
#define PIMG (PADW * PADW)
#define ROWB (PADW * 64 * 2)        // 4352 B per padded NHWC row
#define A_LDS (10 * ROWB)           // 43520 (10 rows: 8 outputs + 2 halo)
#define A_PAD (11 * 256 * 16)       // 45056: pad so staging runs 11 full iters
#define TAPB (64 * 64 * 2)          // 8192 B per weight tap

__device__ __forceinline__ void gld16(const char* g, char* l) {
    __builtin_amdgcn_global_load_lds(
        (const __attribute__((address_space(1))) uint32*)g,
        (__attribute__((address_space(3))) uint32*)l, 16, 0, 0);
}

// ---------------- fused pre-pass: prep_weights + zero_halo + relu_pad -------
__global__ __launch_bounds__(256) void pre_kernel(
    const float* __restrict__ in, const float* __restrict__ a1,
    const float* __restrict__ a2, const float* __restrict__ W,
    __hip_bfloat16* __restrict__ wt, __hip_bfloat16* __restrict__ r0,
    __hip_bfloat16* __restrict__ r1, __hip_bfloat16* __restrict__ r2) {
    __shared__ float tile[32][65];
    int blk = blockIdx.x;
    int tid = threadIdx.x;

    if (blk < 864) {                 // ---- weight prep: plain [l][t][o][i]
        int idx = blk * 256 + tid;   // 6*9*64*64 = 221184 exact
        int i = idx & 63;
        int o = (idx >> 6) & 63;
        int rest = idx >> 12;
        int t = rest % 9;
        int l = rest / 9;
        int ji = i >> 3, jo = o >> 3;
        float ain = 0.f, aout = 0.f;
#pragma unroll
        for (int j = 0; j < 8; ++j) {
            ain  += (j >= ji) ? a1[j] : 0.f;
            aout += (j >= jo) ? a2[j] : 0.f;
        }
        float v = W[(size_t)((l * 64 + o) * 64 + i) * 9 + t] * ain * aout;
        wt[(size_t)(l * 9 + t) * 4096 + o * 64 + i] = __float2bfloat16(v);
    } else if (blk < 992) {          // ---- zero halo ring, image b
        int b = blk - 864;
        __hip_bfloat16* bufs[3] = {r0, r1, r2};
#pragma unroll
        for (int f = 0; f < 3; ++f) {
            uint32* buf = (uint32*)(bufs[f] + (size_t)b * PIMG * 64);
            for (int idx = tid; idx < 132 * 32; idx += 256) {
                int slot = idx >> 5, u = idx & 31;
                int yy, xx;
                if (slot < 34)      { yy = 0;  xx = slot; }
                else if (slot < 68) { yy = 33; xx = slot - 34; }
                else { int s2 = slot - 68; yy = 1 + (s2 >> 1); xx = (s2 & 1) * 33; }
                buf[(size_t)(yy * PADW + xx) * 32 + u] = 0u;
            }
        }
    } else {                         // ---- relu(x) -> padded swizzled NHWC
        int rb = blk - 992;
        int b = rb >> 5, y = rb & 31;
        int x = tid & 31, c0 = tid >> 5;
        const float* ip = in + ((size_t)b * 64 * 32 + y) * 32 + x;
#pragma unroll
        for (int cc = 0; cc < 8; ++cc) {
            int c = cc * 8 + c0;
            tile[x][c] = fmaxf(ip[(size_t)c * 1024], 0.f);
        }
        __syncthreads();
        int o = tid & 63, xg = tid >> 6;
        int p0 = (b * PADW + y + 1) * PADW + 1;
#pragma unroll
        for (int xx = 0; xx < 8; ++xx) {
            int xq = xx * 4 + xg;
            int p = p0 + xq;
            size_t e = (size_t)p * 64 + ((((o >> 3) ^ (p & 7)) << 3) + (o & 7));
            r0[e] = __float2bfloat16(tile[xq][o]);
        }
    }
}

// ---------------- conv stage: barrier-free tap loop -------------------------
// Block: image b = blk>>2, rows y0=(blk&3)*8 .. y0+7. Wave wv: rows y0+2wv,+1.
// A-frag (LDS): l15 = px, quad*8+q*32 = in-ch. B-frag (global/L1): l15 = oc.
// C/D: M(px)=quad*4+r, N(oc)=l15.
template <int NSRC, bool FINAL>
__global__ __launch_bounds__(256) void conv_stage(
    const __hip_bfloat16* __restrict__ s0,
    const __hip_bfloat16* __restrict__ s1,
    const __hip_bfloat16* __restrict__ s2,
    const __hip_bfloat16* __restrict__ wt,
    void* __restrict__ dstv, int l0) {
    __shared__ char smem[A_PAD];
    int tid = threadIdx.x;
    int wv = tid >> 6, lane = tid & 63;
    int quad = lane >> 4, l15 = lane & 15;
    int blk = blockIdx.x;
    int b = blk >> 2, y0 = (blk & 3) << 3;

    const char* srcs[3] = {(const char*)s0, (const char*)s1, (const char*)s2};
    // per-lane B base: + T*TAPB + n*2048 + q*64 selects the fragment chunk
    const char* gB = (const char*)wt + (size_t)l0 * 9 * TAPB +
                     l15 * 128 + quad * 16;

    auto stage_A = [&](int s) {      // 10 rows + pad, linear 16B DMA copy
        const char* gA = srcs[s] + (size_t)(b * PADW + y0) * PADW * 128;
#pragma unroll
        for (int it = 0; it < 11; ++it)
            gld16(gA + (size_t)(it * 256 + tid) * 16,
                  smem + (it * 256 + wv * 64) * 16);
    };

    bf16x8 Bf[2][2][4];              // [ring][q][ntile]
    auto load_B = [&](int T) {
        const char* p = gB + (size_t)T * TAPB;
#pragma unroll
        for (int q = 0; q < 2; ++q)
#pragma unroll
            for (int n = 0; n < 4; ++n)
                Bf[T & 1][q][n] =
                    *(const bf16x8*)(p + n * 2048 + q * 64);
    };

    floatx4 acc[4][4];
#pragma unroll
    for (int m = 0; m < 4; ++m)
#pragma unroll
        for (int n = 0; n < 4; ++n) acc[m][n] = (floatx4){0.f, 0.f, 0.f, 0.f};

    stage_A(0);
    load_B(0);
    __syncthreads();                 // A(src0) staged (drains vmcnt)

#pragma unroll
    for (int T = 0; T < 9 * NSRC; ++T) {
        const int s = T / 9, tl = T % 9, ky = tl / 3, kx = tl % 3;
        if (T + 1 < 9 * NSRC) load_B(T + 1);   // register prefetch, no barrier

#pragma unroll
        for (int q = 0; q < 2; ++q) {
            bf16x8 Af[4];
#pragma unroll
            for (int m = 0; m < 4; ++m) {
                int arow = 2 * wv + (m >> 1) + ky;      // LDS row 0..9
                int apx  = ((m & 1) << 4) + l15 + kx;   // 0..33
                int R = b * PADW + y0 + arow;           // global padded row
                int slot = ((q << 2) + quad) ^ ((2 * R + apx) & 7);
                Af[m] = *(const bf16x8*)(smem + arow * ROWB +
                                         apx * 128 + slot * 16);
            }
#pragma unroll
            for (int m = 0; m < 4; ++m)
#pragma unroll
                for (int n = 0; n < 4; ++n)
                    acc[m][n] = __builtin_amdgcn_mfma_f32_16x16x32_bf16(
                        Af[m], Bf[T & 1][q][n], acc[m][n], 0, 0, 0);
        }

        if (tl == 8 && s + 1 < NSRC) {   // src boundary: swap A tile
            __syncthreads();             // all waves done reading A(s)
            stage_A(s + 1);
            __syncthreads();             // staging drained
        }
    }

    // Epilogue. M(pixel) = quad*4+r (+16 for odd m-tile), N(oc) = n*16+l15.
    if (FINAL) {
        float* out = (float*)dstv;   // fp32 NCHW [128][64][32][32]
#pragma unroll
        for (int m = 0; m < 4; ++m) {
            int row = y0 + 2 * wv + (m >> 1);
#pragma unroll
            for (int n = 0; n < 4; ++n) {
                int o = (n << 4) + l15;
                *(floatx4*)(out + (((size_t)b * 64 + o) * 32 + row) * 32 +
                            ((m & 1) << 4) + (quad << 2)) = acc[m][n];
            }
        }
    } else {
        __hip_bfloat16* out = (__hip_bfloat16*)dstv;  // relu -> swizzled NHWC
#pragma unroll
        for (int m = 0; m < 4; ++m) {
            int row = y0 + 2 * wv + (m >> 1);
#pragma unroll
            for (int n = 0; n < 4; ++n) {
                int o = (n << 4) + l15;
#pragma unroll
                for (int r = 0; r < 4; ++r) {
                    int x = ((m & 1) << 4) + (quad << 2) + r;
                    int p = (b * PADW + row + 1) * PADW + x + 1;
                    float v = fmaxf(acc[m][n][r], 0.f);
                    size_t e = (size_t)p * 64 +
                               ((((o >> 3) ^ (p & 7)) << 3) + (o & 7));
                    out[e] = __float2bfloat16(v);
                }
            }
        }
    }
}

// ---------------------------------------------------------------------------
extern "C" void kernel_launch(void* const* d_in, const int* in_sizes, int n_in,
                              void* d_out, int out_size, void* d_ws,
                              size_t ws_size, hipStream_t stream) {
    const float* inputs  = (const float*)d_in[0];
    const float* alphas1 = (const float*)d_in[1];
    const float* alphas2 = (const float*)d_in[2];
    const float* W       = (const float*)d_in[3];
    char* ws = (char*)d_ws;

    __hip_bfloat16* wt = (__hip_bfloat16*)(ws);                     // 442 KB
    __hip_bfloat16* r0 = (__hip_bfloat16*)(ws + ((size_t)1 << 20)); // 18.9 MB
    __hip_bfloat16* r1 = (__hip_bfloat16*)(ws + ((size_t)20 << 20));
    __hip_bfloat16* r2 = (__hip_bfloat16*)(ws + ((size_t)40 << 20));
    float* out = (float*)d_out;

    pre_kernel<<<864 + 128 + 4096, 256, 0, stream>>>(inputs, alphas1, alphas2,
                                                     W, wt, r0, r1, r2);
    conv_stage<1, false><<<512, 256, 0, stream>>>(r0, r1, r2, wt, (void*)r1, 0);
    conv_stage<2, false><<<512, 256, 0, stream>>>(r0, r1, r2, wt, (void*)r2, 1);
    conv_stage<3, true ><<<512, 256, 0, stream>>>(r0, r1, r2, wt, (void*)out, 3);
}

// Round 6
// 151.008 us; speedup vs baseline: 1.4464x; 1.4464x over previous
//
#include <hip/hip_runtime.h>
#include <hip/hip_bf16.h>

// ---------------------------------------------------------------------------
// InferCellV2 R6: bf16 MFMA implicit GEMM, big-LDS barrier-free source loop.
// Lesson R3/R4: per-tap/per-ky barriers lockstep all 8 waves -> LDS-read and
// MFMA phases serialize (3630 cyc/tap vs ~1400 overlap-ideal). Lesson R5:
// per-lane B gathers from global are 16x cache-line amplified. Fix: stage A
// (18 rows, 76.5KB) AND B (9 taps, 72KB) per SOURCE into 148.5KB dynamic LDS
// (MI355X: 160KB/CU), barriers only at src switches; waves free-run a whole
// src (9 taps x 32 MFMA) and drift into MFMA/LDS overlap (m114).
// Block 512 thr / 8 waves / 16 out rows; grid 256 = 1 block/CU, single round.
// Layouts (verified conflict-free in R3, SQ_LDS_BANK_CONFLICT=0):
//   activations: zero-padded NHWC bf16 [B][34][34][64], chunk cb of pixel p
//     at p*128 + ((cb^(p&7))*16);  weights wt[l][tap][o][i], chunk i>>3 of
//     row o at slot (i>>3)^(o&7). Staging = linear global_load_lds(16B).
// Wave tile 64px x 64oc = 4x4 MFMA 16x16x32, 64 acc VGPRs.
// ---------------------------------------------------------------------------

typedef __bf16 bf16x8 __attribute__((ext_vector_type(8)));
typedef float floatx4 __attribute__((ext_vector_type(4)));
typedef unsigned int uint32;

#define PADW 34
#define PIMG (PADW * PADW)
#define ROWB (PADW * 64 * 2)        // 4352 B per padded NHWC row
#define A_LDS (18 * ROWB)           // 78336 (16 out rows + 2 halo)
#define A_CHUNKS (A_LDS / 16)       // 4896 = 9*512 + 288
#define TAPB (64 * 64 * 2)          // 8192 B per weight tap
#define B_LDS (9 * TAPB)            // 73728
#define B_CHUNKS (B_LDS / 16)       // 4608 = 9*512
#define SMEM_BYTES (A_LDS + B_LDS)  // 152064

__device__ __forceinline__ void gld16(const char* g, char* l) {
    __builtin_amdgcn_global_load_lds(
        (const __attribute__((address_space(1))) uint32*)g,
        (__attribute__((address_space(3))) uint32*)l, 16, 0, 0);
}

// ---------------- fused pre-pass: prep_weights + zero_halo + relu_pad -------
__global__ __launch_bounds__(256) void pre_kernel(
    const float* __restrict__ in, const float* __restrict__ a1,
    const float* __restrict__ a2, const float* __restrict__ W,
    __hip_bfloat16* __restrict__ wt, __hip_bfloat16* __restrict__ r0,
    __hip_bfloat16* __restrict__ r1, __hip_bfloat16* __restrict__ r2) {
    __shared__ float tile[32][65];
    int blk = blockIdx.x;
    int tid = threadIdx.x;

    if (blk < 864) {                 // ---- weights: fold scale + swizzle
        int idx = blk * 256 + tid;   // 6*9*64*64 = 221184 exact
        int i = idx & 63;
        int o = (idx >> 6) & 63;
        int rest = idx >> 12;
        int t = rest % 9;
        int l = rest / 9;
        int ji = i >> 3, jo = o >> 3;
        float ain = 0.f, aout = 0.f;
#pragma unroll
        for (int j = 0; j < 8; ++j) {
            ain  += (j >= ji) ? a1[j] : 0.f;
            aout += (j >= jo) ? a2[j] : 0.f;
        }
        float v = W[(size_t)((l * 64 + o) * 64 + i) * 9 + t] * ain * aout;
        size_t e = (size_t)(l * 9 + t) * 4096 + o * 64 +
                   ((((i >> 3) ^ (o & 7)) << 3) + (i & 7));
        wt[e] = __float2bfloat16(v);
    } else if (blk < 992) {          // ---- zero halo ring, image b
        int b = blk - 864;
        __hip_bfloat16* bufs[3] = {r0, r1, r2};
#pragma unroll
        for (int f = 0; f < 3; ++f) {
            uint32* buf = (uint32*)(bufs[f] + (size_t)b * PIMG * 64);
            for (int idx = tid; idx < 132 * 32; idx += 256) {
                int slot = idx >> 5, u = idx & 31;
                int yy, xx;
                if (slot < 34)      { yy = 0;  xx = slot; }
                else if (slot < 68) { yy = 33; xx = slot - 34; }
                else { int s2 = slot - 68; yy = 1 + (s2 >> 1); xx = (s2 & 1) * 33; }
                buf[(size_t)(yy * PADW + xx) * 32 + u] = 0u;
            }
        }
    } else {                         // ---- relu(x) -> padded swizzled NHWC
        int rb = blk - 992;
        int b = rb >> 5, y = rb & 31;
        int x = tid & 31, c0 = tid >> 5;
        const float* ip = in + ((size_t)b * 64 * 32 + y) * 32 + x;
#pragma unroll
        for (int cc = 0; cc < 8; ++cc) {
            int c = cc * 8 + c0;
            tile[x][c] = fmaxf(ip[(size_t)c * 1024], 0.f);
        }
        __syncthreads();
        int o = tid & 63, xg = tid >> 6;
        int p0 = (b * PADW + y + 1) * PADW + 1;
#pragma unroll
        for (int xx = 0; xx < 8; ++xx) {
            int xq = xx * 4 + xg;
            int p = p0 + xq;
            size_t e = (size_t)p * 64 + ((((o >> 3) ^ (p & 7)) << 3) + (o & 7));
            r0[e] = __float2bfloat16(tile[xq][o]);
        }
    }
}

// ---------------- conv stage: barrier-free within each source ---------------
// Block: image b = blk>>1, strip y0 = (blk&1)*16. Wave wv: rows y0+2wv,+1.
// A-frag: l15 = px, quad*8+q*32 = in-ch. B-frag: l15 = oc. C/D: M=quad*4+r.
template <int NSRC, bool FINAL>
__global__ __launch_bounds__(512, 2) void conv_stage(
    const __hip_bfloat16* __restrict__ s0,
    const __hip_bfloat16* __restrict__ s1,
    const __hip_bfloat16* __restrict__ s2,
    const __hip_bfloat16* __restrict__ wt,
    void* __restrict__ dstv, int l0) {
    extern __shared__ char smem[];               // A_LDS + B_LDS = 152064 B
    char* smemB = smem + A_LDS;
    int tid = threadIdx.x;
    int wv = tid >> 6, lane = tid & 63;
    int quad = lane >> 4, l15 = lane & 15;
    int blk = blockIdx.x;
    int b = blk >> 1, y0 = (blk & 1) << 4;

    const char* srcs[3] = {(const char*)s0, (const char*)s1, (const char*)s2};
    const char* gW = (const char*)wt + (size_t)l0 * 9 * (size_t)TAPB;

    auto stage_A = [&](int s) {      // 18 padded rows, linear 16B DMA copy
        const char* gA = srcs[s] + (size_t)(b * PADW + y0) * PADW * 128;
#pragma unroll
        for (int it = 0; it < 10; ++it) {
            int c = it * 512 + tid;
            if (it < 9 || tid < A_CHUNKS - 9 * 512)
                gld16(gA + (size_t)c * 16, smem + (it * 512 + wv * 64) * 16);
        }
    };
    auto stage_B = [&](int s) {      // 9 taps of src s, linear 16B DMA copy
        const char* gB = gW + (size_t)s * 9 * TAPB;
#pragma unroll
        for (int it = 0; it < 9; ++it) {
            int c = it * 512 + tid;
            gld16(gB + (size_t)c * 16, smemB + (it * 512 + wv * 64) * 16);
        }
    };

    floatx4 acc[4][4];
#pragma unroll
    for (int m = 0; m < 4; ++m)
#pragma unroll
        for (int n = 0; n < 4; ++n) acc[m][n] = (floatx4){0.f, 0.f, 0.f, 0.f};

    stage_A(0);
    stage_B(0);
    __syncthreads();                 // src0 operands resident

#pragma unroll 1
    for (int s = 0; s < NSRC; ++s) {
#pragma unroll
        for (int tl = 0; tl < 9; ++tl) {
            const int ky = tl / 3, kx = tl % 3;
#pragma unroll
            for (int q = 0; q < 2; ++q) {
                bf16x8 Af[4], Bf[4];
#pragma unroll
                for (int m = 0; m < 4; ++m) {
                    int arow = 2 * wv + (m >> 1) + ky;      // LDS row 0..17
                    int apx  = ((m & 1) << 4) + l15 + kx;   // 0..33
                    int R = b * PADW + y0 + arow;           // global padded row
                    int slot = ((q << 2) + quad) ^ ((2 * R + apx) & 7);
                    Af[m] = *(const bf16x8*)(smem + arow * ROWB +
                                             apx * 128 + slot * 16);
                }
#pragma unroll
                for (int n = 0; n < 4; ++n) {
                    int o = (n << 4) + l15;
                    int slot = ((q << 2) + quad) ^ (l15 & 7);
                    Bf[n] = *(const bf16x8*)(smemB + tl * TAPB +
                                             o * 128 + slot * 16);
                }
#pragma unroll
                for (int m = 0; m < 4; ++m)
#pragma unroll
                    for (int n = 0; n < 4; ++n)
                        acc[m][n] = __builtin_amdgcn_mfma_f32_16x16x32_bf16(
                            Af[m], Bf[n], acc[m][n], 0, 0, 0);
            }
        }
        if (s + 1 < NSRC) {          // source switch: the only barriers
            __syncthreads();         // all waves done reading src s operands
            stage_A(s + 1);
            stage_B(s + 1);
            __syncthreads();         // staging drained (vmcnt0 before barrier)
        }
    }

    // Epilogue. M(pixel) = quad*4+r (+16 for odd m-tile), N(oc) = n*16+l15.
    if (FINAL) {
        float* out = (float*)dstv;   // fp32 NCHW [128][64][32][32]
#pragma unroll
        for (int m = 0; m < 4; ++m) {
            int row = y0 + 2 * wv + (m >> 1);
#pragma unroll
            for (int n = 0; n < 4; ++n) {
                int o = (n << 4) + l15;
                *(floatx4*)(out + (((size_t)b * 64 + o) * 32 + row) * 32 +
                            ((m & 1) << 4) + (quad << 2)) = acc[m][n];
            }
        }
    } else {
        __hip_bfloat16* out = (__hip_bfloat16*)dstv;  // relu -> swizzled NHWC
#pragma unroll
        for (int m = 0; m < 4; ++m) {
            int row = y0 + 2 * wv + (m >> 1);
#pragma unroll
            for (int n = 0; n < 4; ++n) {
                int o = (n << 4) + l15;
#pragma unroll
                for (int r = 0; r < 4; ++r) {
                    int x = ((m & 1) << 4) + (quad << 2) + r;
                    int p = (b * PADW + row + 1) * PADW + x + 1;
                    float v = fmaxf(acc[m][n][r], 0.f);
                    size_t e = (size_t)p * 64 +
                               ((((o >> 3) ^ (p & 7)) << 3) + (o & 7));
                    out[e] = __float2bfloat16(v);
                }
            }
        }
    }
}

// ---------------------------------------------------------------------------
extern "C" void kernel_launch(void* const* d_in, const int* in_sizes, int n_in,
                              void* d_out, int out_size, void* d_ws,
                              size_t ws_size, hipStream_t stream) {
    const float* inputs  = (const float*)d_in[0];
    const float* alphas1 = (const float*)d_in[1];
    const float* alphas2 = (const float*)d_in[2];
    const float* W       = (const float*)d_in[3];
    char* ws = (char*)d_ws;

    __hip_bfloat16* wt = (__hip_bfloat16*)(ws);                     // 442 KB
    __hip_bfloat16* r0 = (__hip_bfloat16*)(ws + ((size_t)1 << 20)); // 18.9 MB
    __hip_bfloat16* r1 = (__hip_bfloat16*)(ws + ((size_t)20 << 20));
    __hip_bfloat16* r2 = (__hip_bfloat16*)(ws + ((size_t)40 << 20));
    float* out = (float*)d_out;

    // Opt-in to >64KB dynamic LDS (idempotent; harmless under graph capture).
    (void)hipFuncSetAttribute((const void*)conv_stage<1, false>,
                              hipFuncAttributeMaxDynamicSharedMemorySize,
                              SMEM_BYTES);
    (void)hipFuncSetAttribute((const void*)conv_stage<2, false>,
                              hipFuncAttributeMaxDynamicSharedMemorySize,
                              SMEM_BYTES);
    (void)hipFuncSetAttribute((const void*)conv_stage<3, true>,
                              hipFuncAttributeMaxDynamicSharedMemorySize,
                              SMEM_BYTES);

    pre_kernel<<<864 + 128 + 4096, 256, 0, stream>>>(inputs, alphas1, alphas2,
                                                     W, wt, r0, r1, r2);
    conv_stage<1, false><<<256, 512, SMEM_BYTES, stream>>>(r0, r1, r2, wt,
                                                           (void*)r1, 0);
    conv_stage<2, false><<<256, 512, SMEM_BYTES, stream>>>(r0, r1, r2, wt,
                                                           (void*)r2, 1);
    conv_stage<3, true ><<<256, 512, SMEM_BYTES, stream>>>(r0, r1, r2, wt,
                                                           (void*)out, 3);
}